// Round 1
// baseline (452.235 us; speedup 1.0000x reference)
//
#include <hip/hip_runtime.h>
#include <hip/hip_bf16.h>

#define BB 4096
#define DIMM 768
#define NHEADS 8
#define DHEAD 96
#define NIDS 751
#define QKSCALE 0.10206207261596577f   // 96^-0.5
#define PVCH 96

typedef _Float16 f16x8 __attribute__((ext_vector_type(8)));
typedef float f32x4 __attribute__((ext_vector_type(4)));

__device__ __forceinline__ void split2(float v, _Float16* hi, _Float16* lo) {
    _Float16 h = (_Float16)v;
    *hi = h;
    *lo = (_Float16)((v - (float)h) * 2048.0f);
}

__device__ __forceinline__ float rec2(const _Float16* hi, const _Float16* lo, size_t idx) {
    return (float)hi[idx] + (float)lo[idx] * (1.0f / 2048.0f);
}

__global__ void k_zero(float* p, int n) {
    int i = blockIdx.x * blockDim.x + threadIdx.x;
    if (i < n) p[i] = 0.0f;
}

__global__ void k_split(const float* __restrict__ in, _Float16* __restrict__ hi,
                        _Float16* __restrict__ lo, float s, int n) {
    int i = blockIdx.x * blockDim.x + threadIdx.x;
    if (i < n) split2(in[i] * s, &hi[i], &lo[i]);
}

// W[K][N] -> Th/Tl [N][K] (scaled split), 32x32 tiles via LDS
__global__ void k_tsplit(const float* __restrict__ W, _Float16* __restrict__ Th,
                         _Float16* __restrict__ Tl, float s, int K, int N) {
    __shared__ float tile[32][33];
    int k0 = blockIdx.y * 32, n0 = blockIdx.x * 32;
    int tx = threadIdx.x, ty = threadIdx.y;
    for (int r = ty; r < 32; r += 8) tile[r][tx] = W[(size_t)(k0 + r) * N + n0 + tx];
    __syncthreads();
    for (int r = ty; r < 32; r += 8) {
        int n = n0 + r, k = k0 + tx;
        split2(tile[tx][r] * s, &Th[(size_t)n * K + k], &Tl[(size_t)n * K + k]);
    }
}

// counting sort of labels into groups; single block
__global__ void k_groups(const int* __restrict__ labels, int* __restrict__ perm,
                         int* __restrict__ gstart, int* __restrict__ gcnt) {
    __shared__ int cnt[NIDS], start[NIDS], cur[NIDS];
    int tid = threadIdx.x;
    for (int i = tid; i < NIDS; i += 1024) { cnt[i] = 0; cur[i] = 0; }
    __syncthreads();
    for (int i = tid; i < BB; i += 1024) atomicAdd(&cnt[labels[i]], 1);
    __syncthreads();
    if (tid == 0) { int s = 0; for (int i = 0; i < NIDS; i++) { start[i] = s; s += cnt[i]; } }
    __syncthreads();
    for (int i = tid; i < BB; i += 1024) {
        int lb = labels[i];
        int p = start[lb] + atomicAdd(&cur[lb], 1);
        perm[p] = i;
    }
    for (int i = tid; i < NIDS; i += 1024) { gstart[i] = start[i]; gcnt[i] = cnt[i]; }
}

// C = A(M,K) * B(N,K)^T via split-f16 MFMA; symmetric fragment loads so only the
// verified C/D layout (col=lane&15, row=(lane>>4)*4+reg) is assumed.
// EPI 0: qkv write (n<1536 -> QK split store scaled x16; else v fp32)
// EPI 1: plain fp32 C store
// EPI 2: rowwise sum of exp(d*QKSCALE) atomically into lsum[head*BB+m]
template <int EPI>
__global__ __launch_bounds__(256) void k_gemm(
    const _Float16* __restrict__ Ah, const _Float16* __restrict__ Al, int lda,
    const _Float16* __restrict__ Bh, const _Float16* __restrict__ Bl, int ldb,
    int K, float inv,
    float* __restrict__ outF, _Float16* __restrict__ oh, _Float16* __restrict__ ol,
    float* __restrict__ lsum) {
    __shared__ __align__(16) _Float16 sAh[64][40];
    __shared__ __align__(16) _Float16 sAl[64][40];
    __shared__ __align__(16) _Float16 sBh[64][40];
    __shared__ __align__(16) _Float16 sBl[64][40];
    const int tid = threadIdx.x;
    const int lane = tid & 63;
    const int wave = tid >> 6;
    const int wm = wave >> 1, wn = wave & 1;
    const int m0 = blockIdx.y * 64, n0 = blockIdx.x * 64;
    const int head = blockIdx.z;
    const int cA = (EPI == 2) ? head * DHEAD : 0;
    const int cB = (EPI == 2) ? DIMM + head * DHEAD : 0;
    const int srow = tid >> 2;
    const int scol = (tid & 3) * 8;
    const int g8 = (lane >> 4) * 8;
    const int rl = lane & 15;

    f32x4 acc0[2][2], acc1[2][2];
    const f32x4 vzero = {0.f, 0.f, 0.f, 0.f};
#pragma unroll
    for (int a = 0; a < 2; a++)
#pragma unroll
        for (int b = 0; b < 2; b++) { acc0[a][b] = vzero; acc1[a][b] = vzero; }

    for (int kk = 0; kk < K; kk += 32) {
        *(f16x8*)&sAh[srow][scol] = *(const f16x8*)(Ah + (size_t)(m0 + srow) * lda + cA + kk + scol);
        *(f16x8*)&sAl[srow][scol] = *(const f16x8*)(Al + (size_t)(m0 + srow) * lda + cA + kk + scol);
        *(f16x8*)&sBh[srow][scol] = *(const f16x8*)(Bh + (size_t)(n0 + srow) * ldb + cB + kk + scol);
        *(f16x8*)&sBl[srow][scol] = *(const f16x8*)(Bl + (size_t)(n0 + srow) * ldb + cB + kk + scol);
        __syncthreads();
        f16x8 ah[2], al[2], bh[2], bl[2];
#pragma unroll
        for (int t = 0; t < 2; t++) {
            ah[t] = *(const f16x8*)&sAh[wm * 32 + t * 16 + rl][g8];
            al[t] = *(const f16x8*)&sAl[wm * 32 + t * 16 + rl][g8];
            bh[t] = *(const f16x8*)&sBh[wn * 32 + t * 16 + rl][g8];
            bl[t] = *(const f16x8*)&sBl[wn * 32 + t * 16 + rl][g8];
        }
#pragma unroll
        for (int a = 0; a < 2; a++)
#pragma unroll
            for (int b = 0; b < 2; b++) {
                acc0[a][b] = __builtin_amdgcn_mfma_f32_16x16x32_f16(ah[a], bh[b], acc0[a][b], 0, 0, 0);
                acc1[a][b] = __builtin_amdgcn_mfma_f32_16x16x32_f16(ah[a], bl[b], acc1[a][b], 0, 0, 0);
                acc1[a][b] = __builtin_amdgcn_mfma_f32_16x16x32_f16(al[a], bh[b], acc1[a][b], 0, 0, 0);
            }
        __syncthreads();
    }

    if constexpr (EPI == 2) {
#pragma unroll
        for (int a = 0; a < 2; a++) {
            f32x4 es = {0.f, 0.f, 0.f, 0.f};
#pragma unroll
            for (int b = 0; b < 2; b++) {
                f32x4 d = (acc0[a][b] + acc1[a][b] * (1.0f / 2048.0f)) * inv;
#pragma unroll
                for (int r = 0; r < 4; r++) es[r] += __expf(d[r] * QKSCALE);
            }
#pragma unroll
            for (int m = 1; m < 16; m <<= 1) {
#pragma unroll
                for (int r = 0; r < 4; r++) es[r] += __shfl_xor(es[r], m);
            }
            if (rl == 0) {
                int mb = m0 + wm * 32 + a * 16 + (lane >> 4) * 4;
#pragma unroll
                for (int r = 0; r < 4; r++)
                    atomicAdd(&lsum[(size_t)head * BB + mb + r], es[r]);
            }
        }
    } else {
#pragma unroll
        for (int a = 0; a < 2; a++)
#pragma unroll
            for (int b = 0; b < 2; b++) {
                f32x4 d = (acc0[a][b] + acc1[a][b] * (1.0f / 2048.0f)) * inv;
                int n = n0 + wn * 32 + b * 16 + rl;
                int mb = m0 + wm * 32 + a * 16 + (lane >> 4) * 4;
#pragma unroll
                for (int r = 0; r < 4; r++) {
                    int m = mb + r;
                    if constexpr (EPI == 0) {
                        if (n < 1536) {
                            split2(d[r] * 16.0f, &oh[(size_t)m * 1536 + n], &ol[(size_t)m * 1536 + n]);
                        } else {
                            outF[(size_t)m * DIMM + (n - 1536)] = d[r];
                        }
                    } else {
                        outF[(size_t)m * DIMM + n] = d[r];
                    }
                }
            }
    }
}

// masked PV: block per row i; waves 0..7 compute attn weights for their head over
// the row's label-group; all 768 threads accumulate O[i][h*96+d].
__global__ __launch_bounds__(768) void k_pv(
    const _Float16* __restrict__ QKh, const _Float16* __restrict__ QKl,
    const float* __restrict__ vbuf, const float* __restrict__ lsum,
    const int* __restrict__ labels, const int* __restrict__ perm,
    const int* __restrict__ gstart, const int* __restrict__ gcnt,
    _Float16* __restrict__ oh, _Float16* __restrict__ ol) {
    const int i = blockIdx.x;
    const int tid = threadIdx.x;
    const int wave = tid >> 6;
    const int lane = tid & 63;
    __shared__ float wv[NHEADS][PVCH];
    __shared__ int pidx[PVCH];
    const int lab = labels[i];
    const int st = gstart[lab];
    const int cnt = gcnt[lab];

    float q0 = 0.f, q1 = 0.f, invl = 0.f;
    if (wave < NHEADS) {
        size_t base = (size_t)i * 1536 + wave * DHEAD;
        q0 = rec2(QKh, QKl, base + lane);
        if (lane < 32) q1 = rec2(QKh, QKl, base + 64 + lane);
        invl = 1.0f / lsum[(size_t)wave * BB + i];
    }
    const int h = tid / DHEAD;
    float acc = 0.f;
    for (int b0 = 0; b0 < cnt; b0 += PVCH) {
        int ch = cnt - b0; if (ch > PVCH) ch = PVCH;
        __syncthreads();
        if (tid < ch) pidx[tid] = perm[st + b0 + tid];
        __syncthreads();
        if (wave < NHEADS) {
            for (int jj = 0; jj < ch; jj++) {
                size_t kb = (size_t)pidx[jj] * 1536 + DIMM + wave * DHEAD;
                float p = q0 * rec2(QKh, QKl, kb + lane);
                if (lane < 32) p += q1 * rec2(QKh, QKl, kb + 64 + lane);
#pragma unroll
                for (int m = 32; m >= 1; m >>= 1) p += __shfl_xor(p, m);
                if (lane == 0)
                    wv[wave][jj] = __expf(p * (1.0f / 256.0f) * QKSCALE) * invl;
            }
        }
        __syncthreads();
        for (int jj = 0; jj < ch; jj++)
            acc += wv[h][jj] * vbuf[(size_t)pidx[jj] * DIMM + tid];
    }
    split2(acc * 16.0f, &oh[(size_t)i * DIMM + tid], &ol[(size_t)i * DIMM + tid]);
}

extern "C" void kernel_launch(void* const* d_in, const int* in_sizes, int n_in,
                              void* d_out, int out_size, void* d_ws, size_t ws_size,
                              hipStream_t stream) {
    const float* x = (const float*)d_in[0];
    const int* labels = (const int*)d_in[1];  // harness converts integer inputs to int32
    const float* Wqkv = (const float*)d_in[2];
    const float* Wout = (const float*)d_in[3];
    float* out = (float*)d_out;

    char* ws = (char*)d_ws;
    size_t off = 0;
    auto alloc = [&](size_t bytes) -> void* {
        void* p = ws + off;
        off += (bytes + 255) & ~(size_t)255;
        return p;
    };
    _Float16* Xh   = (_Float16*)alloc((size_t)BB * DIMM * 2);
    _Float16* Xl   = (_Float16*)alloc((size_t)BB * DIMM * 2);
    _Float16* WqTh = (_Float16*)alloc((size_t)2304 * DIMM * 2);
    _Float16* WqTl = (_Float16*)alloc((size_t)2304 * DIMM * 2);
    _Float16* WoTh = (_Float16*)alloc((size_t)DIMM * DIMM * 2);
    _Float16* WoTl = (_Float16*)alloc((size_t)DIMM * DIMM * 2);
    _Float16* QKh  = (_Float16*)alloc((size_t)BB * 1536 * 2);
    _Float16* QKl  = (_Float16*)alloc((size_t)BB * 1536 * 2);
    float* vbuf    = (float*)alloc((size_t)BB * DIMM * 4);
    float* lsum    = (float*)alloc((size_t)NHEADS * BB * 4);
    _Float16* Oh   = (_Float16*)alloc((size_t)BB * DIMM * 2);
    _Float16* Ol   = (_Float16*)alloc((size_t)BB * DIMM * 2);
    int* perm      = (int*)alloc(BB * 4);
    int* gstart    = (int*)alloc(1024 * 4);
    int* gcnt      = (int*)alloc(1024 * 4);

    k_zero<<<dim3((NHEADS * BB + 255) / 256), dim3(256), 0, stream>>>(lsum, NHEADS * BB);
    k_split<<<dim3((BB * DIMM + 255) / 256), dim3(256), 0, stream>>>(x, Xh, Xl, 16.0f, BB * DIMM);
    k_tsplit<<<dim3(2304 / 32, DIMM / 32), dim3(32, 8), 0, stream>>>(Wqkv, WqTh, WqTl, 256.0f, DIMM, 2304);
    k_tsplit<<<dim3(DIMM / 32, DIMM / 32), dim3(32, 8), 0, stream>>>(Wout, WoTh, WoTl, 256.0f, DIMM, DIMM);
    k_groups<<<dim3(1), dim3(1024), 0, stream>>>(labels, perm, gstart, gcnt);

    // qkv = x @ Wqkv : A scale 16, B scale 256 -> inv 1/4096
    k_gemm<0><<<dim3(2304 / 64, BB / 64, 1), dim3(256), 0, stream>>>(
        Xh, Xl, DIMM, WqTh, WqTl, DIMM, DIMM, 1.0f / 4096.0f, vbuf, QKh, QKl, nullptr);
    // row sums of exp(q.k * scale): A,B scale 16 -> inv 1/256
    k_gemm<2><<<dim3(BB / 64, BB / 64, NHEADS), dim3(256), 0, stream>>>(
        QKh, QKl, 1536, QKh, QKl, 1536, DHEAD, 1.0f / 256.0f, nullptr, nullptr, nullptr, lsum);
    // masked PV
    k_pv<<<dim3(BB), dim3(768), 0, stream>>>(QKh, QKl, vbuf, lsum, labels, perm, gstart, gcnt, Oh, Ol);
    // out = O @ Wout : inv 1/4096
    k_gemm<1><<<dim3(DIMM / 64, BB / 64, 1), dim3(256), 0, stream>>>(
        Oh, Ol, DIMM, WoTh, WoTl, DIMM, DIMM, 1.0f / 4096.0f, out, nullptr, nullptr, nullptr);
}

// Round 2
// 387.661 us; speedup vs baseline: 1.1666x; 1.1666x over previous
//
#include <hip/hip_runtime.h>
#include <hip/hip_bf16.h>

#define BB 4096
#define DIMM 768
#define NHEADS 8
#define DHEAD 96
#define NIDS 751
#define QKSCALE 0.10206207261596577f   // 96^-0.5
#define PVCH 96

typedef _Float16 f16x8 __attribute__((ext_vector_type(8)));
typedef float f32x4 __attribute__((ext_vector_type(4)));

// split-f16: hi = rte(v), lo = residual (UNscaled — stays f16-normal for our
// pre-scaled operands; lets all 3 split MFMAs share ONE fp32 accumulator)
__device__ __forceinline__ void split2(float v, _Float16* hi, _Float16* lo) {
    _Float16 h = (_Float16)v;
    *hi = h;
    *lo = (_Float16)(v - (float)h);
}

__device__ __forceinline__ float rec2(const _Float16* hi, const _Float16* lo, size_t idx) {
    return (float)hi[idx] + (float)lo[idx];
}

__device__ __forceinline__ void gl_lds16(const void* g, void* l) {
    __builtin_amdgcn_global_load_lds(
        (const __attribute__((address_space(1))) unsigned int*)g,
        (__attribute__((address_space(3))) unsigned int*)l, 16, 0, 0);
}

__global__ void k_zero(float* p, int n) {
    int i = blockIdx.x * blockDim.x + threadIdx.x;
    if (i < n) p[i] = 0.0f;
}

__global__ void k_split(const float* __restrict__ in, _Float16* __restrict__ hi,
                        _Float16* __restrict__ lo, float s, int n) {
    int i = blockIdx.x * blockDim.x + threadIdx.x;
    if (i < n) split2(in[i] * s, &hi[i], &lo[i]);
}

// W[K][N] -> Th/Tl [N][K] (scaled split), 32x32 tiles via LDS
__global__ void k_tsplit(const float* __restrict__ W, _Float16* __restrict__ Th,
                         _Float16* __restrict__ Tl, float s, int K, int N) {
    __shared__ float tile[32][33];
    int k0 = blockIdx.y * 32, n0 = blockIdx.x * 32;
    int tx = threadIdx.x, ty = threadIdx.y;
    for (int r = ty; r < 32; r += 8) tile[r][tx] = W[(size_t)(k0 + r) * N + n0 + tx];
    __syncthreads();
    for (int r = ty; r < 32; r += 8) {
        int n = n0 + r, k = k0 + tx;
        split2(tile[tx][r] * s, &Th[(size_t)n * K + k], &Tl[(size_t)n * K + k]);
    }
}

// counting sort of labels into groups; single block
__global__ void k_groups(const int* __restrict__ labels, int* __restrict__ perm,
                         int* __restrict__ gstart, int* __restrict__ gcnt) {
    __shared__ int cnt[NIDS], start[NIDS], cur[NIDS];
    int tid = threadIdx.x;
    for (int i = tid; i < NIDS; i += 1024) { cnt[i] = 0; cur[i] = 0; }
    __syncthreads();
    for (int i = tid; i < BB; i += 1024) atomicAdd(&cnt[labels[i]], 1);
    __syncthreads();
    if (tid == 0) { int s = 0; for (int i = 0; i < NIDS; i++) { start[i] = s; s += cnt[i]; } }
    __syncthreads();
    for (int i = tid; i < BB; i += 1024) {
        int lb = labels[i];
        int p = start[lb] + atomicAdd(&cur[lb], 1);
        perm[p] = i;
    }
    for (int i = tid; i < NIDS; i += 1024) { gstart[i] = start[i]; gcnt[i] = cnt[i]; }
}

// C = A(M,K) * B(N,K)^T via split-f16 MFMA, 128x128 tile, BK=32, 4 waves.
// m97 structure: linear LDS + global_load_lds width=16, 2-barrier K-loop.
// Symmetric A/B fragment loads; only the m89-verified C/D layout is assumed
// (col=lane&15, row=(lane>>4)*4+reg).
// EPI 0: qkv write (n<1536 -> QK split store scaled x16; else v fp32)
// EPI 1: plain fp32 C store
// EPI 2: rowwise sum of exp(d*inv*QKSCALE) atomically into lsum[head*BB+m]
template <int EPI>
__global__ __launch_bounds__(256) void k_gemm(
    const _Float16* __restrict__ Ah, const _Float16* __restrict__ Al, int lda,
    const _Float16* __restrict__ Bh, const _Float16* __restrict__ Bl, int ldb,
    int K, float inv,
    float* __restrict__ outF, _Float16* __restrict__ oh, _Float16* __restrict__ ol,
    float* __restrict__ lsum) {
    __shared__ __align__(16) _Float16 sAh[128 * 32];
    __shared__ __align__(16) _Float16 sAl[128 * 32];
    __shared__ __align__(16) _Float16 sBh[128 * 32];
    __shared__ __align__(16) _Float16 sBl[128 * 32];
    const int tid = threadIdx.x;
    const int lane = tid & 63;
    const int wave = tid >> 6;
    const int wm = wave >> 1, wn = wave & 1;
    const int m0 = blockIdx.y * 128, n0 = blockIdx.x * 128;
    const int head = blockIdx.z;
    const int cA = (EPI == 2) ? head * DHEAD : 0;
    const int cB = (EPI == 2) ? DIMM + head * DHEAD : 0;
    const int srow = tid >> 2;          // 0..63 (two 64-row rounds per tile)
    const int scol = (tid & 3) * 8;     // f16 col offset, 16B granules
    const int rl = lane & 15;
    const int g8 = (lane >> 4) * 8;

    // staging source pointers (row part fixed; add kk per step)
    const _Float16* gAh0 = Ah + (size_t)(m0 + srow) * lda + cA + scol;
    const _Float16* gAh1 = gAh0 + (size_t)64 * lda;
    const _Float16* gAl0 = Al + (size_t)(m0 + srow) * lda + cA + scol;
    const _Float16* gAl1 = gAl0 + (size_t)64 * lda;
    const _Float16* gBh0 = Bh + (size_t)(n0 + srow) * ldb + cB + scol;
    const _Float16* gBh1 = gBh0 + (size_t)64 * ldb;
    const _Float16* gBl0 = Bl + (size_t)(n0 + srow) * ldb + cB + scol;
    const _Float16* gBl1 = gBl0 + (size_t)64 * ldb;
    // LDS dest: linear, = wave-uniform base + lane*16B (gl_lds requirement)
    const int d0 = tid * 8, d1 = 2048 + tid * 8;

    f32x4 acc[4][4];
    const f32x4 vzero = {0.f, 0.f, 0.f, 0.f};
#pragma unroll
    for (int a = 0; a < 4; a++)
#pragma unroll
        for (int b = 0; b < 4; b++) acc[a][b] = vzero;

    for (int kk = 0; kk < K; kk += 32) {
        __syncthreads();   // previous step's LDS reads done before overwrite
        gl_lds16(gAh0 + kk, sAh + d0);
        gl_lds16(gAh1 + kk, sAh + d1);
        gl_lds16(gAl0 + kk, sAl + d0);
        gl_lds16(gAl1 + kk, sAl + d1);
        gl_lds16(gBh0 + kk, sBh + d0);
        gl_lds16(gBh1 + kk, sBh + d1);
        gl_lds16(gBl0 + kk, sBl + d0);
        gl_lds16(gBl1 + kk, sBl + d1);
        __syncthreads();   // compiler drains vmcnt(0) before barrier

        f16x8 ah[4], al[4], bh[4], bl[4];
#pragma unroll
        for (int t = 0; t < 4; t++) {
            ah[t] = *(const f16x8*)&sAh[(wm * 64 + t * 16 + rl) * 32 + g8];
            al[t] = *(const f16x8*)&sAl[(wm * 64 + t * 16 + rl) * 32 + g8];
            bh[t] = *(const f16x8*)&sBh[(wn * 64 + t * 16 + rl) * 32 + g8];
            bl[t] = *(const f16x8*)&sBl[(wn * 64 + t * 16 + rl) * 32 + g8];
        }
#pragma unroll
        for (int a = 0; a < 4; a++)
#pragma unroll
            for (int b = 0; b < 4; b++) {
                acc[a][b] = __builtin_amdgcn_mfma_f32_16x16x32_f16(ah[a], bh[b], acc[a][b], 0, 0, 0);
                acc[a][b] = __builtin_amdgcn_mfma_f32_16x16x32_f16(ah[a], bl[b], acc[a][b], 0, 0, 0);
                acc[a][b] = __builtin_amdgcn_mfma_f32_16x16x32_f16(al[a], bh[b], acc[a][b], 0, 0, 0);
            }
    }

    if constexpr (EPI == 2) {
        const float esc = inv * QKSCALE;
#pragma unroll
        for (int a = 0; a < 4; a++) {
            f32x4 es = {0.f, 0.f, 0.f, 0.f};
#pragma unroll
            for (int b = 0; b < 4; b++) {
#pragma unroll
                for (int r = 0; r < 4; r++) es[r] += __expf(acc[a][b][r] * esc);
            }
#pragma unroll
            for (int m = 1; m < 16; m <<= 1) {
#pragma unroll
                for (int r = 0; r < 4; r++) es[r] += __shfl_xor(es[r], m);
            }
            if (rl == 0) {
                int mb = m0 + wm * 64 + a * 16 + (lane >> 4) * 4;
#pragma unroll
                for (int r = 0; r < 4; r++)
                    atomicAdd(&lsum[(size_t)head * BB + mb + r], es[r]);
            }
        }
    } else {
#pragma unroll
        for (int a = 0; a < 4; a++)
#pragma unroll
            for (int b = 0; b < 4; b++) {
                f32x4 d = acc[a][b] * inv;
                int n = n0 + wn * 64 + b * 16 + rl;
                int mb = m0 + wm * 64 + a * 16 + (lane >> 4) * 4;
#pragma unroll
                for (int r = 0; r < 4; r++) {
                    int m = mb + r;
                    if constexpr (EPI == 0) {
                        if (n < 1536) {
                            split2(d[r] * 16.0f, &oh[(size_t)m * 1536 + n], &ol[(size_t)m * 1536 + n]);
                        } else {
                            outF[(size_t)m * DIMM + (n - 1536)] = d[r];
                        }
                    } else {
                        outF[(size_t)m * DIMM + n] = d[r];
                    }
                }
            }
    }
}

// masked PV: block per row i; waves 0..7 compute attn weights for their head over
// the row's label-group; all 768 threads accumulate O[i][h*96+d].
__global__ __launch_bounds__(768) void k_pv(
    const _Float16* __restrict__ QKh, const _Float16* __restrict__ QKl,
    const float* __restrict__ vbuf, const float* __restrict__ lsum,
    const int* __restrict__ labels, const int* __restrict__ perm,
    const int* __restrict__ gstart, const int* __restrict__ gcnt,
    _Float16* __restrict__ oh, _Float16* __restrict__ ol) {
    const int i = blockIdx.x;
    const int tid = threadIdx.x;
    const int wave = tid >> 6;
    const int lane = tid & 63;
    __shared__ float wv[NHEADS][PVCH];
    __shared__ int pidx[PVCH];
    const int lab = labels[i];
    const int st = gstart[lab];
    const int cnt = gcnt[lab];

    float q0 = 0.f, q1 = 0.f, invl = 0.f;
    if (wave < NHEADS) {
        size_t base = (size_t)i * 1536 + wave * DHEAD;
        q0 = rec2(QKh, QKl, base + lane);
        if (lane < 32) q1 = rec2(QKh, QKl, base + 64 + lane);
        invl = 1.0f / lsum[(size_t)wave * BB + i];
    }
    const int h = tid / DHEAD;
    float acc = 0.f;
    for (int b0 = 0; b0 < cnt; b0 += PVCH) {
        int ch = cnt - b0; if (ch > PVCH) ch = PVCH;
        __syncthreads();
        if (tid < ch) pidx[tid] = perm[st + b0 + tid];
        __syncthreads();
        if (wave < NHEADS) {
            for (int jj = 0; jj < ch; jj++) {
                size_t kb = (size_t)pidx[jj] * 1536 + DIMM + wave * DHEAD;
                float p = q0 * rec2(QKh, QKl, kb + lane);
                if (lane < 32) p += q1 * rec2(QKh, QKl, kb + 64 + lane);
#pragma unroll
                for (int m = 32; m >= 1; m >>= 1) p += __shfl_xor(p, m);
                if (lane == 0)
                    wv[wave][jj] = __expf(p * (1.0f / 256.0f) * QKSCALE) * invl;
            }
        }
        __syncthreads();
        for (int jj = 0; jj < ch; jj++)
            acc += wv[h][jj] * vbuf[(size_t)pidx[jj] * DIMM + tid];
    }
    split2(acc * 16.0f, &oh[(size_t)i * DIMM + tid], &ol[(size_t)i * DIMM + tid]);
}

extern "C" void kernel_launch(void* const* d_in, const int* in_sizes, int n_in,
                              void* d_out, int out_size, void* d_ws, size_t ws_size,
                              hipStream_t stream) {
    const float* x = (const float*)d_in[0];
    const int* labels = (const int*)d_in[1];
    const float* Wqkv = (const float*)d_in[2];
    const float* Wout = (const float*)d_in[3];
    float* out = (float*)d_out;

    char* ws = (char*)d_ws;
    size_t off = 0;
    auto alloc = [&](size_t bytes) -> void* {
        void* p = ws + off;
        off += (bytes + 255) & ~(size_t)255;
        return p;
    };
    _Float16* Xh   = (_Float16*)alloc((size_t)BB * DIMM * 2);
    _Float16* Xl   = (_Float16*)alloc((size_t)BB * DIMM * 2);
    _Float16* WqTh = (_Float16*)alloc((size_t)2304 * DIMM * 2);
    _Float16* WqTl = (_Float16*)alloc((size_t)2304 * DIMM * 2);
    _Float16* WoTh = (_Float16*)alloc((size_t)DIMM * DIMM * 2);
    _Float16* WoTl = (_Float16*)alloc((size_t)DIMM * DIMM * 2);
    _Float16* QKh  = (_Float16*)alloc((size_t)BB * 1536 * 2);
    _Float16* QKl  = (_Float16*)alloc((size_t)BB * 1536 * 2);
    float* vbuf    = (float*)alloc((size_t)BB * DIMM * 4);
    float* lsum    = (float*)alloc((size_t)NHEADS * BB * 4);
    _Float16* Oh   = (_Float16*)alloc((size_t)BB * DIMM * 2);
    _Float16* Ol   = (_Float16*)alloc((size_t)BB * DIMM * 2);
    int* perm      = (int*)alloc(BB * 4);
    int* gstart    = (int*)alloc(1024 * 4);
    int* gcnt      = (int*)alloc(1024 * 4);

    k_zero<<<dim3((NHEADS * BB + 255) / 256), dim3(256), 0, stream>>>(lsum, NHEADS * BB);
    k_split<<<dim3((BB * DIMM + 255) / 256), dim3(256), 0, stream>>>(x, Xh, Xl, 16.0f, BB * DIMM);
    k_tsplit<<<dim3(2304 / 32, DIMM / 32), dim3(32, 8), 0, stream>>>(Wqkv, WqTh, WqTl, 256.0f, DIMM, 2304);
    k_tsplit<<<dim3(DIMM / 32, DIMM / 32), dim3(32, 8), 0, stream>>>(Wout, WoTh, WoTl, 256.0f, DIMM, DIMM);
    k_groups<<<dim3(1), dim3(1024), 0, stream>>>(labels, perm, gstart, gcnt);

    // qkv = x @ Wqkv : A scale 16, B scale 256 -> inv 1/4096
    k_gemm<0><<<dim3(2304 / 128, BB / 128, 1), dim3(256), 0, stream>>>(
        Xh, Xl, DIMM, WqTh, WqTl, DIMM, DIMM, 1.0f / 4096.0f, vbuf, QKh, QKl, nullptr);
    // row sums of exp(q.k * scale): A,B scale 16 -> inv 1/256
    k_gemm<2><<<dim3(BB / 128, BB / 128, NHEADS), dim3(256), 0, stream>>>(
        QKh, QKl, 1536, QKh, QKl, 1536, DHEAD, 1.0f / 256.0f, nullptr, nullptr, nullptr, lsum);
    // masked PV
    k_pv<<<dim3(BB), dim3(768), 0, stream>>>(QKh, QKl, vbuf, lsum, labels, perm, gstart, gcnt, Oh, Ol);
    // out = O @ Wout : inv 1/4096
    k_gemm<1><<<dim3(DIMM / 128, BB / 128, 1), dim3(256), 0, stream>>>(
        Oh, Ol, DIMM, WoTh, WoTl, DIMM, DIMM, 1.0f / 4096.0f, out, nullptr, nullptr, nullptr);
}